// Round 6
// baseline (865.016 us; speedup 1.0000x reference)
//
#include <hip/hip_runtime.h>

// HeteroSAGE on MI355X — round 6: R5 async-staging structure + grid-size fix.
// R5 post-mortem: absmax 4.85e-3 failure was NOT the async GEMM — it was
// f32_to_bf16 launched with truncated grids (N_CARD*64/8/256 = 1562.5 -> 1562),
// leaving the tails of card_embb (3024 elems) and merch_embb (2048 elems) as
// 0xAA poison => ~80 corrupted embedding rows => small sprinkled logit errors.
// Fix: ceil-div the convert grids. GEMM: global->LDS via global_load_lds
// width=16 (16 async 1KB loads/wave, one drain/barrier), compile-time K.

#define N_TX    200000
#define N_CARD  50000
#define N_MERCH 10000
#define NE      200000

typedef __attribute__((ext_vector_type(8))) short short8;
typedef __attribute__((ext_vector_type(4))) short short4v;
typedef __attribute__((ext_vector_type(4))) float f32x4;

__device__ inline unsigned short f2b(float f) {
    unsigned u = __builtin_bit_cast(unsigned, f);
    unsigned r = (u + 0x7fffu + ((u >> 16) & 1u)) >> 16;   // RNE
    return (unsigned short)r;
}
__device__ inline float b2f(unsigned short s) {
    return __builtin_bit_cast(float, (unsigned)s << 16);
}

__device__ __forceinline__ void load_lds16(const void* g, void* l) {
    __builtin_amdgcn_global_load_lds(
        (const __attribute__((address_space(1))) unsigned int*)g,
        (__attribute__((address_space(3))) unsigned int*)l,
        16, 0, 0);
}

// ---------------------------------------------------------------------------
// OUT[M,128] = act( A1[rowIdx1]@W1 (+ A2@W2) + bias + P1[I1[r]] + P2[I2[r]] )
// optional head: out[r] = relu(row).h2W + h2b (fp32). All A/W/P bf16.
// WT* = weights transposed [N=128][K]. Block: 128 rows x 128 cols, 4 waves.
template <int K>
__global__ __launch_bounds__(256, 2) void mfma_gemm(
    const unsigned short* __restrict__ A1, const int* __restrict__ rowIdx1,
    const unsigned short* __restrict__ WT1,
    const unsigned short* __restrict__ A2, const unsigned short* __restrict__ WT2,
    const float* __restrict__ bias,
    const unsigned short* __restrict__ P1, const int* __restrict__ I1,
    const unsigned short* __restrict__ P2, const int* __restrict__ I2,
    int do_relu, const float* __restrict__ h2W, const float* __restrict__ h2b,
    void* __restrict__ OUT, int M)
{
    constexpr int RPG = 1024 / (K * 2);   // rows per 1KB staging group (4 or 8)
    constexpr int NG  = 128 / RPG;        // groups per tile (32 or 16)
    constexpr int GPW = NG / 4;           // groups per wave (8 or 4)
    constexpr int GS  = 1040;             // group stride bytes (1KB + 16B pad)
    constexpr int NKK = K / 32;           // MFMA k-steps (4 or 2)
    constexpr int LSH = (K == 128) ? 4 : 3;   // lanes-per-row shift

    __shared__ __align__(16) char smem[66560];
    char* Asb = smem;                      // NG*GS bytes
    char* Wsb = smem + NG * GS;            // NG*GS bytes
    float* Os = (float*)smem;              // [128][130] fp32 (overlay)

    const int tid  = threadIdx.x;
    const int wave = tid >> 6;
    const int lane = tid & 63;
    const int quad = lane >> 4;
    const int l15  = lane & 15;
    const int base = blockIdx.x * 128;

    const int lrow = lane >> LSH;                       // row within group
    const int lcol = (lane & ((1 << LSH) - 1)) * 8;     // shorts within row

    f32x4 acc[2][8];
#pragma unroll
    for (int mt = 0; mt < 2; ++mt)
#pragma unroll
        for (int nt = 0; nt < 8; ++nt)
            acc[mt][nt] = (f32x4){0.f, 0.f, 0.f, 0.f};

#pragma unroll
    for (int pass = 0; pass < 2; ++pass) {
        const unsigned short* Ag = (pass == 0) ? A1 : A2;
        if (!Ag) break;
        const unsigned short* Wg = (pass == 0) ? WT1 : WT2;
        const int* rIdx = (pass == 0) ? rowIdx1 : nullptr;

        __syncthreads();   // previous pass/phase LDS reads complete

        // ---- async stage W tile: GPW x 1KB per wave, back-to-back ----
#pragma unroll
        for (int i = 0; i < GPW; ++i) {
            int g = wave * GPW + i;
            load_lds16(Wg + g * 512 + lane * 8, Wsb + g * GS);
        }
        // ---- async stage A tile (per-lane row addresses) ----
#pragma unroll
        for (int i = 0; i < GPW; ++i) {
            int g = wave * GPW + i;
            int gr = base + g * RPG + lrow;
            int grc = (gr < M) ? gr : (M - 1);
            int ar = rIdx ? rIdx[grc] : grc;
            load_lds16(Ag + (size_t)ar * K + lcol, Asb + g * GS);
        }
        __syncthreads();   // drains vmcnt: all LDS-bound loads landed

        // ---- fragments from LDS + MFMA ----
        short8 af[2][NKK];
#pragma unroll
        for (int mt = 0; mt < 2; ++mt) {
            int r = wave * 32 + mt * 16 + l15;
            const char* ap = Asb + (r / RPG) * GS + (r % RPG) * (2 * K) + quad * 16;
#pragma unroll
            for (int kk = 0; kk < NKK; ++kk)
                af[mt][kk] = *reinterpret_cast<const short8*>(ap + kk * 64);
        }
#pragma unroll
        for (int nt = 0; nt < 8; ++nt) {
            int n = nt * 16 + l15;
            const char* bp = Wsb + (n / RPG) * GS + (n % RPG) * (2 * K) + quad * 16;
            short8 bf[NKK];
#pragma unroll
            for (int kk = 0; kk < NKK; ++kk)
                bf[kk] = *reinterpret_cast<const short8*>(bp + kk * 64);
#pragma unroll
            for (int mt = 0; mt < 2; ++mt)
#pragma unroll
                for (int kk = 0; kk < NKK; ++kk)
                    acc[mt][nt] = __builtin_amdgcn_mfma_f32_16x16x32_bf16(
                        af[mt][kk], bf[kk], acc[mt][nt], 0, 0, 0);
        }
    }

    // ---- epilogue phase 1: acc (+bias) -> LDS fp32 tile [128][130] ----
    float bias_v[8];
#pragma unroll
    for (int nt = 0; nt < 8; ++nt)
        bias_v[nt] = bias ? bias[nt * 16 + l15] : 0.f;

    __syncthreads();
#pragma unroll
    for (int mt = 0; mt < 2; ++mt) {
        int rbase = wave * 32 + mt * 16 + quad * 4;
#pragma unroll
        for (int reg = 0; reg < 4; ++reg)
#pragma unroll
            for (int nt = 0; nt < 8; ++nt)
                Os[(rbase + reg) * 130 + nt * 16 + l15] =
                    acc[mt][nt][reg] + bias_v[nt];
    }
    __syncthreads();

    // ---- epilogue phase 2: coalesced read-out, P-gathers, relu, store ----
    const int col4 = (tid & 31) * 4;
    float4 h2w4 = make_float4(0.f, 0.f, 0.f, 0.f);
    if (h2W) h2w4 = *reinterpret_cast<const float4*>(h2W + col4);
    unsigned short* OUTb = (unsigned short*)OUT;
    float* OUTf = (float*)OUT;

#pragma unroll
    for (int it = 0; it < 16; ++it) {
        int row = it * 8 + (tid >> 5);
        int gr = base + row;
        bool valid = gr < M;
        int grc = valid ? gr : 0;
        float4 o = *reinterpret_cast<const float4*>(&Os[row * 130 + col4]);
        if (P1) {
            size_t ix = (size_t)(I1 ? I1[grc] : grc) * 128 + col4;
            short4v p = *reinterpret_cast<const short4v*>(P1 + ix);
            o.x += b2f((unsigned short)p[0]); o.y += b2f((unsigned short)p[1]);
            o.z += b2f((unsigned short)p[2]); o.w += b2f((unsigned short)p[3]);
        }
        if (P2) {
            size_t ix = (size_t)(I2 ? I2[grc] : grc) * 128 + col4;
            short4v p = *reinterpret_cast<const short4v*>(P2 + ix);
            o.x += b2f((unsigned short)p[0]); o.y += b2f((unsigned short)p[1]);
            o.z += b2f((unsigned short)p[2]); o.w += b2f((unsigned short)p[3]);
        }
        if (do_relu) {
            o.x = fmaxf(o.x, 0.f); o.y = fmaxf(o.y, 0.f);
            o.z = fmaxf(o.z, 0.f); o.w = fmaxf(o.w, 0.f);
        }
        if (h2W) {
            float s = o.x * h2w4.x + o.y * h2w4.y + o.z * h2w4.z + o.w * h2w4.w;
            s += __shfl_xor(s, 1);  s += __shfl_xor(s, 2);
            s += __shfl_xor(s, 4);  s += __shfl_xor(s, 8);
            s += __shfl_xor(s, 16);
            if ((tid & 31) == 0 && valid) OUTf[gr] = s + h2b[0];
        } else if (valid) {
            short4v t;
            t[0] = (short)f2b(o.x); t[1] = (short)f2b(o.y);
            t[2] = (short)f2b(o.z); t[3] = (short)f2b(o.w);
            *reinterpret_cast<short4v*>(OUTb + (size_t)gr * 128 + col4) = t;
        }
    }
}

// ---------------------------------------------------------------------------
// fp32 -> bf16 streaming convert (8 elems/thread); n must be a multiple of 8
__global__ __launch_bounds__(256) void f32_to_bf16(
    const float* __restrict__ src, unsigned short* __restrict__ dst, int n)
{
    int i = (blockIdx.x * 256 + threadIdx.x) * 8;
    if (i >= n) return;
    float4 u = *reinterpret_cast<const float4*>(src + i);
    float4 v = *reinterpret_cast<const float4*>(src + i + 4);
    short8 t;
    t[0] = (short)f2b(u.x); t[1] = (short)f2b(u.y);
    t[2] = (short)f2b(u.z); t[3] = (short)f2b(u.w);
    t[4] = (short)f2b(v.x); t[5] = (short)f2b(v.y);
    t[6] = (short)f2b(v.z); t[7] = (short)f2b(v.w);
    *reinterpret_cast<short8*>(dst + i) = t;
}

// ---------------------------------------------------------------------------
// Weight prep: fp32 [K][128] -> bf16 transposed [128][K]; jobs (6,13) also
// build Wsum=Wr0+Wr2 / bsum=bl0+bl2. 18 jobs x 16384-short slots.
__global__ __launch_bounds__(256) void convert_weights(
    const float* __restrict__ tx_W, const float* __restrict__ card_proj_W,
    const float* __restrict__ merch_proj_W, const float* __restrict__ h1_W,
    const float* __restrict__ conv_Wl, const float* __restrict__ conv_Wr,
    const float* __restrict__ conv_bl,
    unsigned short* __restrict__ WT, float* __restrict__ bsum)
{
    int job = blockIdx.y;
    int K = 128;
    const float* src = nullptr;
    const float* src2 = nullptr;
    if (job == 0) src = tx_W;
    else if (job == 1) { src = card_proj_W; K = 64; }
    else if (job == 2) { src = merch_proj_W; K = 64; }
    else if (job == 3) src = h1_W;
    else {
        int l = (job - 4) / 7, e = (job - 4) % 7;
        const float* Wl = conv_Wl + (size_t)l * 4 * 16384;
        const float* Wr = conv_Wr + (size_t)l * 4 * 16384;
        switch (e) {
            case 0: src = Wl; break;
            case 1: src = Wl + 16384; break;
            case 2: src = Wl + 2 * 16384; break;
            case 3: src = Wl + 3 * 16384; break;
            case 4: src = Wr + 16384; break;
            case 5: src = Wr + 3 * 16384; break;
            default:
                src = Wr; src2 = Wr + 2 * 16384;
                if (blockIdx.x == 0 && threadIdx.x < 128) {
                    const float* bl = conv_bl + (size_t)l * 4 * 128;
                    bsum[l * 128 + threadIdx.x] =
                        bl[threadIdx.x] + bl[2 * 128 + threadIdx.x];
                }
                break;
        }
    }
    int e = blockIdx.x * 256 + threadIdx.x;
    if (e < (K << 7)) {
        int n = (K == 128) ? (e >> 7) : (e >> 6);
        int k = e & (K - 1);
        float v = src[(size_t)k * 128 + n];
        if (src2) v += src2[(size_t)k * 128 + n];
        WT[(size_t)job * 16384 + n * K + k] = f2b(v);
    }
}

// ---------------------------------------------------------------------------
// CSR build (edges fixed within call; reused across layers)
__global__ __launch_bounds__(256) void hist_kernel(
    const int* __restrict__ e_card, const int* __restrict__ e_merch,
    int* __restrict__ hist_c, int* __restrict__ hist_m, int E)
{
    int i = blockIdx.x * 256 + threadIdx.x;
    if (i < E) {
        atomicAdd(&hist_c[e_card[i]], 1);
        atomicAdd(&hist_m[e_merch[i]], 1);
    }
}

__global__ __launch_bounds__(1024) void scan2_kernel(
    const int* __restrict__ hist_c, int* __restrict__ offs_c, int* __restrict__ cur_c, int nc,
    const int* __restrict__ hist_m, int* __restrict__ offs_m, int* __restrict__ cur_m, int nm)
{
    const int* hist = (blockIdx.x == 0) ? hist_c : hist_m;
    int* offs = (blockIdx.x == 0) ? offs_c : offs_m;
    int* cursor = (blockIdx.x == 0) ? cur_c : cur_m;
    int n = (blockIdx.x == 0) ? nc : nm;
    __shared__ int wsum[16];
    __shared__ int s_carry;
    const int tid = threadIdx.x, lane = tid & 63, wid = tid >> 6;
    if (tid == 0) s_carry = 0;
    __syncthreads();
    for (int base = 0; base < n; base += 1024) {
        int i = base + tid;
        int v = (i < n) ? hist[i] : 0;
        int x = v;
#pragma unroll
        for (int d = 1; d < 64; d <<= 1) {
            int t = __shfl_up(x, d);
            if (lane >= d) x += t;
        }
        if (lane == 63) wsum[wid] = x;
        __syncthreads();
        if (wid == 0) {
            int y = (lane < 16) ? wsum[lane] : 0;
#pragma unroll
            for (int d = 1; d < 16; d <<= 1) {
                int t = __shfl_up(y, d);
                if (lane >= d) y += t;
            }
            if (lane < 16) wsum[lane] = y;
        }
        __syncthreads();
        int wbase = (wid > 0) ? wsum[wid - 1] : 0;
        int excl = s_carry + wbase + x - v;
        if (i < n) { offs[i] = excl; cursor[i] = excl; }
        __syncthreads();
        if (tid == 0) s_carry += wsum[15];
        __syncthreads();
    }
    if (threadIdx.x == 0) offs[n] = s_carry;
}

__global__ __launch_bounds__(256) void place_kernel(
    const int* __restrict__ e_card, const int* __restrict__ e_tx_c,
    const int* __restrict__ e_merch, const int* __restrict__ e_tx_m,
    int* __restrict__ cur_c, int* __restrict__ eidx_c,
    int* __restrict__ cur_m, int* __restrict__ eidx_m, int E)
{
    int i = blockIdx.x * 256 + threadIdx.x;
    if (i < E) {
        int pc = atomicAdd(&cur_c[e_card[i]], 1);
        eidx_c[pc] = e_tx_c[i];
        int pm = atomicAdd(&cur_m[e_merch[i]], 1);
        eidx_m[pm] = e_tx_m[i];
    }
}

// one wave per dst node: mean of gathered bf16 h rows (4B/lane, coalesced)
__global__ __launch_bounds__(256) void gather_mean(
    const unsigned short* __restrict__ h_src, const int* __restrict__ offs,
    const int* __restrict__ eidx, unsigned short* __restrict__ out_mean, int n_dst)
{
    const int lane = threadIdx.x & 63;
    const int d = blockIdx.x * 4 + (threadIdx.x >> 6);
    if (d >= n_dst) return;
    const int s = offs[d], e = offs[d + 1];
    float a0 = 0.f, a1 = 0.f;
    for (int p = s; p < e; ++p) {
        int tx = eidx[p];
        unsigned v = *reinterpret_cast<const unsigned*>(
            h_src + (size_t)tx * 128 + lane * 2);
        a0 += b2f((unsigned short)(v & 0xffff));
        a1 += b2f((unsigned short)(v >> 16));
    }
    const float inv = (e > s) ? 1.0f / (float)(e - s) : 0.f;
    unsigned o = ((unsigned)f2b(a1 * inv) << 16) | f2b(a0 * inv);
    *reinterpret_cast<unsigned*>(out_mean + (size_t)d * 128 + lane * 2) = o;
}

// ---------------------------------------------------------------------------
extern "C" void kernel_launch(void* const* d_in, const int* in_sizes, int n_in,
                              void* d_out, int out_size, void* d_ws, size_t ws_size,
                              hipStream_t stream)
{
    const float* tx_x        = (const float*)d_in[0];
    const int*   card_ids    = (const int*)d_in[1];
    const int*   merch_ids   = (const int*)d_in[2];
    const int*   e_card      = (const int*)d_in[3];
    const int*   e_tx_c      = (const int*)d_in[4];
    const int*   e_merch     = (const int*)d_in[5];
    const int*   e_tx_m      = (const int*)d_in[6];
    const float* card_emb    = (const float*)d_in[7];
    const float* merch_emb   = (const float*)d_in[8];
    const float* card_proj_W = (const float*)d_in[9];
    const float* card_proj_b = (const float*)d_in[10];
    const float* merch_proj_W= (const float*)d_in[11];
    const float* merch_proj_b= (const float*)d_in[12];
    const float* tx_W        = (const float*)d_in[13];
    const float* tx_b        = (const float*)d_in[14];
    const float* conv_Wl     = (const float*)d_in[15];
    const float* conv_bl     = (const float*)d_in[16];
    const float* conv_Wr     = (const float*)d_in[17];
    const float* h1_W        = (const float*)d_in[18];
    const float* h1_b        = (const float*)d_in[19];
    const float* h2_W        = (const float*)d_in[20];
    const float* h2_b        = (const float*)d_in[21];

    char* wsb = (char*)d_ws;
    auto alloc = [&](size_t bytes) {
        char* p = wsb; wsb += (bytes + 255) & ~(size_t)255; return p;
    };
    unsigned short* tx_xb      = (unsigned short*)alloc((size_t)N_TX * 128 * 2);
    unsigned short* card_embb  = (unsigned short*)alloc((size_t)N_CARD * 64 * 2);
    unsigned short* merch_embb = (unsigned short*)alloc((size_t)N_MERCH * 64 * 2);
    unsigned short* h_tx       = (unsigned short*)alloc((size_t)N_TX * 128 * 2);
    unsigned short* h_card     = (unsigned short*)alloc((size_t)N_CARD * 128 * 2);
    unsigned short* h_merch    = (unsigned short*)alloc((size_t)N_MERCH * 128 * 2);
    unsigned short* p_card     = (unsigned short*)alloc((size_t)N_CARD * 128 * 2);
    unsigned short* p_merch    = (unsigned short*)alloc((size_t)N_MERCH * 128 * 2);
    unsigned short* mean_card  = (unsigned short*)alloc((size_t)N_CARD * 128 * 2);
    unsigned short* mean_merch = (unsigned short*)alloc((size_t)N_MERCH * 128 * 2);
    unsigned short* WT         = (unsigned short*)alloc((size_t)18 * 16384 * 2);
    float* bsum = (float*)alloc(2 * 128 * 4);
    int* hist_c = (int*)alloc((size_t)(N_CARD + N_MERCH) * 4);  // one memset
    int* hist_m = hist_c + N_CARD;
    int* offs_c = (int*)alloc((size_t)(N_CARD + 1) * 4);
    int* cur_c  = (int*)alloc((size_t)N_CARD * 4);
    int* eidx_c = (int*)alloc((size_t)NE * 4);
    int* offs_m = (int*)alloc((size_t)(N_MERCH + 1) * 4);
    int* cur_m  = (int*)alloc((size_t)N_MERCH * 4);
    int* eidx_m = (int*)alloc((size_t)NE * 4);

    auto WTj = [&](int job) { return WT + (size_t)job * 16384; };

    auto gemm128 = [&](const unsigned short* A1, const int* ri,
                       const unsigned short* W1, const unsigned short* A2,
                       const unsigned short* W2, const float* bias,
                       const unsigned short* P1, const int* I1,
                       const unsigned short* P2, const int* I2, int relu,
                       const float* h2w, const float* h2bb, void* out, int M) {
        mfma_gemm<128><<<dim3((M + 127) / 128), dim3(256), 0, stream>>>(
            A1, ri, W1, A2, W2, bias, P1, I1, P2, I2, relu, h2w, h2bb, out, M);
    };
    auto gemm64 = [&](const unsigned short* A1, const int* ri,
                      const unsigned short* W1, const float* bias,
                      int relu, void* out, int M) {
        mfma_gemm<64><<<dim3((M + 127) / 128), dim3(256), 0, stream>>>(
            A1, ri, W1, nullptr, nullptr, bias, nullptr, nullptr,
            nullptr, nullptr, relu, nullptr, nullptr, out, M);
    };
    auto cvt = [&](const float* s, unsigned short* d, int n) {
        f32_to_bf16<<<dim3((n / 8 + 255) / 256), dim3(256), 0, stream>>>(s, d, n);
    };

    // weight prep + activation converts + CSR build
    convert_weights<<<dim3(64, 18), dim3(256), 0, stream>>>(
        tx_W, card_proj_W, merch_proj_W, h1_W, conv_Wl, conv_Wr, conv_bl,
        WT, bsum);
    cvt(tx_x, tx_xb, N_TX * 128);           // ceil-div grids (R5 bug fix)
    cvt(card_emb, card_embb, N_CARD * 64);
    cvt(merch_emb, merch_embb, N_MERCH * 64);
    hipMemsetAsync(hist_c, 0, (size_t)(N_CARD + N_MERCH) * 4, stream);
    hist_kernel<<<dim3((NE + 255) / 256), dim3(256), 0, stream>>>(
        e_card, e_merch, hist_c, hist_m, NE);
    scan2_kernel<<<dim3(2), dim3(1024), 0, stream>>>(
        hist_c, offs_c, cur_c, N_CARD, hist_m, offs_m, cur_m, N_MERCH);
    place_kernel<<<dim3((NE + 255) / 256), dim3(256), 0, stream>>>(
        e_card, e_tx_c, e_merch, e_tx_m, cur_c, eidx_c, cur_m, eidx_m, NE);

    // input encoders
    gemm128(tx_xb, nullptr, WTj(0), nullptr, nullptr, tx_b,
            nullptr, nullptr, nullptr, nullptr, 1, nullptr, nullptr, h_tx, N_TX);
    gemm64(card_embb, card_ids, WTj(1), card_proj_b, 0, h_card, N_CARD);
    gemm64(merch_embb, merch_ids, WTj(2), merch_proj_b, 0, h_merch, N_MERCH);

    for (int l = 0; l < 2; ++l) {
        const float* bl = conv_bl + (size_t)l * 4 * 128;
        int j = 4 + l * 7;   // Wl0,Wl1,Wl2,Wl3,Wr1,Wr3,Wsum

        gather_mean<<<dim3((N_CARD + 3) / 4), dim3(256), 0, stream>>>(
            h_tx, offs_c, eidx_c, mean_card, N_CARD);
        gather_mean<<<dim3((N_MERCH + 3) / 4), dim3(256), 0, stream>>>(
            h_tx, offs_m, eidx_m, mean_merch, N_MERCH);

        // p_* = h_* @ Wl[0/2] (pre-update hidden) for the tx-side gather
        gemm128(h_card, nullptr, WTj(j + 0), nullptr, nullptr, nullptr,
                nullptr, nullptr, nullptr, nullptr, 0, nullptr, nullptr,
                p_card, N_CARD);
        gemm128(h_merch, nullptr, WTj(j + 2), nullptr, nullptr, nullptr,
                nullptr, nullptr, nullptr, nullptr, 0, nullptr, nullptr,
                p_merch, N_MERCH);

        // card/merch updates: relu(mean@Wl + h@Wr + bl)  (in-place, row-local)
        gemm128(mean_card, nullptr, WTj(j + 1), h_card, WTj(j + 4),
                bl + 1 * 128, nullptr, nullptr, nullptr, nullptr, 1,
                nullptr, nullptr, h_card, N_CARD);
        gemm128(mean_merch, nullptr, WTj(j + 3), h_merch, WTj(j + 5),
                bl + 3 * 128, nullptr, nullptr, nullptr, nullptr, 1,
                nullptr, nullptr, h_merch, N_MERCH);

        // tx update: relu(h_tx@(Wr0+Wr2) + bl0+bl2 + p_card[e_card] + p_merch[e_merch])
        gemm128(h_tx, nullptr, WTj(j + 6), nullptr, nullptr, bsum + l * 128,
                p_card, e_card, p_merch, e_merch, 1, nullptr, nullptr,
                h_tx, N_TX);
    }

    // head: logits = relu(h_tx @ h1_W + h1_b) @ h2_W + h2_b  (fp32 out)
    gemm128(h_tx, nullptr, WTj(3), nullptr, nullptr, h1_b,
            nullptr, nullptr, nullptr, nullptr, 1, h2_W, h2_b, d_out, N_TX);
}

// Round 7
// 858.776 us; speedup vs baseline: 1.0073x; 1.0073x over previous
//
#include <hip/hip_runtime.h>

// HeteroSAGE on MI355X — round 7: occupancy-first MFMA GEMM.
// R6 post-mortem: R3/R4/R6 (three different data paths) all pinned at
// ~105us/big-GEMM with MfmaUtil 2.2%, VALUBusy 9%, HBM 14%, occupancy 17%.
// Invariant = 66KB LDS -> 2 blocks/CU + barrier-serialized block chain with
// no K-loop: CUs idle at barriers. Fix: W never goes to LDS (B-frags direct
// from global, L1-resident 32KB table; A's DMA staging bypasses L1), A-only
// LDS (33KB) + two-half fp32 epilogue overlay => 33.8KB LDS = 4 blocks/CU,
// 16 waves/CU, launch_bounds(256,4).

#define N_TX    200000
#define N_CARD  50000
#define N_MERCH 10000
#define NE      200000

typedef __attribute__((ext_vector_type(8))) short short8;
typedef __attribute__((ext_vector_type(4))) short short4v;
typedef __attribute__((ext_vector_type(4))) float f32x4;

__device__ inline unsigned short f2b(float f) {
    unsigned u = __builtin_bit_cast(unsigned, f);
    unsigned r = (u + 0x7fffu + ((u >> 16) & 1u)) >> 16;   // RNE
    return (unsigned short)r;
}
__device__ inline float b2f(unsigned short s) {
    return __builtin_bit_cast(float, (unsigned)s << 16);
}

__device__ __forceinline__ void load_lds16(const void* g, void* l) {
    __builtin_amdgcn_global_load_lds(
        (const __attribute__((address_space(1))) unsigned int*)g,
        (__attribute__((address_space(3))) unsigned int*)l,
        16, 0, 0);
}

// ---------------------------------------------------------------------------
// OUT[M,128] = act( A1[rowIdx1]@W1 (+ A2@W2) + bias + P1[I1[r]] + P2[I2[r]] )
// optional head: out[r] = relu(row).h2W + h2b (fp32). All A/W/P bf16.
// WT* = weights transposed [N=128][K]. Block: 128 rows x 128 cols, 4 waves.
template <int K>
__global__ __launch_bounds__(256, 4) void mfma_gemm(
    const unsigned short* __restrict__ A1, const int* __restrict__ rowIdx1,
    const unsigned short* __restrict__ WT1,
    const unsigned short* __restrict__ A2, const unsigned short* __restrict__ WT2,
    const float* __restrict__ bias,
    const unsigned short* __restrict__ P1, const int* __restrict__ I1,
    const unsigned short* __restrict__ P2, const int* __restrict__ I2,
    int do_relu, const float* __restrict__ h2W, const float* __restrict__ h2b,
    void* __restrict__ OUT, int M)
{
    constexpr int RPG = 1024 / (K * 2);   // rows per 1KB staging group (4 or 8)
    constexpr int NG  = 128 / RPG;        // groups per tile (32 or 16)
    constexpr int GPW = NG / 4;           // groups per wave (8 or 4)
    constexpr int GS  = 1040;             // group stride bytes (1KB + 16B pad)
    constexpr int NKK = K / 32;           // MFMA k-steps (4 or 2)
    constexpr int LSH = (K == 128) ? 4 : 3;   // lanes-per-row shift

    __shared__ __align__(16) char smem[33792];   // A tile (<=33280) | Os half
    char* Asb = smem;
    float* Os = (float*)smem;                    // [64][132] fp32 epilogue half

    const int tid  = threadIdx.x;
    const int wave = tid >> 6;
    const int lane = tid & 63;
    const int quad = lane >> 4;
    const int l15  = lane & 15;
    const int base = blockIdx.x * 128;

    const int lrow = lane >> LSH;                       // row within group
    const int lcol = (lane & ((1 << LSH) - 1)) * 8;     // shorts within row

    f32x4 acc[2][8];
#pragma unroll
    for (int mt = 0; mt < 2; ++mt)
#pragma unroll
        for (int nt = 0; nt < 8; ++nt)
            acc[mt][nt] = (f32x4){0.f, 0.f, 0.f, 0.f};

#pragma unroll
    for (int pass = 0; pass < 2; ++pass) {
        const unsigned short* Ag = (pass == 0) ? A1 : A2;
        if (!Ag) break;
        const unsigned short* Wg = (pass == 0) ? WT1 : WT2;
        const int* rIdx = (pass == 0) ? rowIdx1 : nullptr;

        __syncthreads();   // previous pass LDS reads complete

        // ---- async stage A tile (GPW x 1KB per wave, back-to-back) ----
#pragma unroll
        for (int i = 0; i < GPW; ++i) {
            int g = wave * GPW + i;
            int gr = base + g * RPG + lrow;
            int grc = (gr < M) ? gr : (M - 1);
            int ar = rIdx ? rIdx[grc] : grc;
            load_lds16(Ag + (size_t)ar * K + lcol, Asb + g * GS);
        }
        __syncthreads();   // drains vmcnt: A landed in LDS

        // ---- MFMA: af from LDS per kk, bf direct from global (L1-hot) ----
#pragma unroll
        for (int kk = 0; kk < NKK; ++kk) {
            short8 af[2];
#pragma unroll
            for (int mt = 0; mt < 2; ++mt) {
                int r = wave * 32 + mt * 16 + l15;
                af[mt] = *reinterpret_cast<const short8*>(
                    Asb + (r / RPG) * GS + (r % RPG) * (2 * K) + kk * 64 + quad * 16);
            }
#pragma unroll
            for (int nt = 0; nt < 8; ++nt) {
                short8 bf = *reinterpret_cast<const short8*>(
                    Wg + (size_t)(nt * 16 + l15) * K + kk * 32 + quad * 8);
#pragma unroll
                for (int mt = 0; mt < 2; ++mt)
                    acc[mt][nt] = __builtin_amdgcn_mfma_f32_16x16x32_bf16(
                        af[mt], bf, acc[mt][nt], 0, 0, 0);
            }
        }
    }

    // ---- epilogue: two 64-row halves through fp32 LDS (overlays A) ----
    float bias_v[8];
#pragma unroll
    for (int nt = 0; nt < 8; ++nt)
        bias_v[nt] = bias ? bias[nt * 16 + l15] : 0.f;

    const int col4 = (tid & 31) * 4;
    float4 h2w4 = make_float4(0.f, 0.f, 0.f, 0.f);
    if (h2W) h2w4 = *reinterpret_cast<const float4*>(h2W + col4);
    unsigned short* OUTb = (unsigned short*)OUT;
    float* OUTf = (float*)OUT;

#pragma unroll
    for (int half = 0; half < 2; ++half) {
        __syncthreads();   // prior reads (A frags / prev half) complete
        if ((wave >> 1) == half) {
            int wl = (wave & 1) * 32;              // local row base of this wave
#pragma unroll
            for (int mt = 0; mt < 2; ++mt) {
                int rbase = wl + mt * 16 + quad * 4;
#pragma unroll
                for (int reg = 0; reg < 4; ++reg)
#pragma unroll
                    for (int nt = 0; nt < 8; ++nt)
                        Os[(rbase + reg) * 132 + nt * 16 + l15] =
                            acc[mt][nt][reg] + bias_v[nt];
            }
        }
        __syncthreads();
#pragma unroll
        for (int it = 0; it < 8; ++it) {
            int lr = it * 8 + (tid >> 5);
            int gr = base + half * 64 + lr;
            bool valid = gr < M;
            int grc = valid ? gr : 0;
            float4 o = *reinterpret_cast<const float4*>(&Os[lr * 132 + col4]);
            if (P1) {
                size_t ix = (size_t)(I1 ? I1[grc] : grc) * 128 + col4;
                short4v p = *reinterpret_cast<const short4v*>(P1 + ix);
                o.x += b2f((unsigned short)p[0]); o.y += b2f((unsigned short)p[1]);
                o.z += b2f((unsigned short)p[2]); o.w += b2f((unsigned short)p[3]);
            }
            if (P2) {
                size_t ix = (size_t)(I2 ? I2[grc] : grc) * 128 + col4;
                short4v p = *reinterpret_cast<const short4v*>(P2 + ix);
                o.x += b2f((unsigned short)p[0]); o.y += b2f((unsigned short)p[1]);
                o.z += b2f((unsigned short)p[2]); o.w += b2f((unsigned short)p[3]);
            }
            if (do_relu) {
                o.x = fmaxf(o.x, 0.f); o.y = fmaxf(o.y, 0.f);
                o.z = fmaxf(o.z, 0.f); o.w = fmaxf(o.w, 0.f);
            }
            if (h2W) {
                float s = o.x * h2w4.x + o.y * h2w4.y + o.z * h2w4.z + o.w * h2w4.w;
                s += __shfl_xor(s, 1);  s += __shfl_xor(s, 2);
                s += __shfl_xor(s, 4);  s += __shfl_xor(s, 8);
                s += __shfl_xor(s, 16);
                if ((tid & 31) == 0 && valid) OUTf[gr] = s + h2b[0];
            } else if (valid) {
                short4v t;
                t[0] = (short)f2b(o.x); t[1] = (short)f2b(o.y);
                t[2] = (short)f2b(o.z); t[3] = (short)f2b(o.w);
                *reinterpret_cast<short4v*>(OUTb + (size_t)gr * 128 + col4) = t;
            }
        }
    }
}

// ---------------------------------------------------------------------------
// fp32 -> bf16 streaming convert (8 elems/thread); n multiple of 8
__global__ __launch_bounds__(256) void f32_to_bf16(
    const float* __restrict__ src, unsigned short* __restrict__ dst, int n)
{
    int i = (blockIdx.x * 256 + threadIdx.x) * 8;
    if (i >= n) return;
    float4 u = *reinterpret_cast<const float4*>(src + i);
    float4 v = *reinterpret_cast<const float4*>(src + i + 4);
    short8 t;
    t[0] = (short)f2b(u.x); t[1] = (short)f2b(u.y);
    t[2] = (short)f2b(u.z); t[3] = (short)f2b(u.w);
    t[4] = (short)f2b(v.x); t[5] = (short)f2b(v.y);
    t[6] = (short)f2b(v.z); t[7] = (short)f2b(v.w);
    *reinterpret_cast<short8*>(dst + i) = t;
}

// ---------------------------------------------------------------------------
// Weight prep: fp32 [K][128] -> bf16 transposed [128][K]; jobs (6,13) also
// build Wsum=Wr0+Wr2 / bsum=bl0+bl2. 18 jobs x 16384-short slots.
__global__ __launch_bounds__(256) void convert_weights(
    const float* __restrict__ tx_W, const float* __restrict__ card_proj_W,
    const float* __restrict__ merch_proj_W, const float* __restrict__ h1_W,
    const float* __restrict__ conv_Wl, const float* __restrict__ conv_Wr,
    const float* __restrict__ conv_bl,
    unsigned short* __restrict__ WT, float* __restrict__ bsum)
{
    int job = blockIdx.y;
    int K = 128;
    const float* src = nullptr;
    const float* src2 = nullptr;
    if (job == 0) src = tx_W;
    else if (job == 1) { src = card_proj_W; K = 64; }
    else if (job == 2) { src = merch_proj_W; K = 64; }
    else if (job == 3) src = h1_W;
    else {
        int l = (job - 4) / 7, e = (job - 4) % 7;
        const float* Wl = conv_Wl + (size_t)l * 4 * 16384;
        const float* Wr = conv_Wr + (size_t)l * 4 * 16384;
        switch (e) {
            case 0: src = Wl; break;
            case 1: src = Wl + 16384; break;
            case 2: src = Wl + 2 * 16384; break;
            case 3: src = Wl + 3 * 16384; break;
            case 4: src = Wr + 16384; break;
            case 5: src = Wr + 3 * 16384; break;
            default:
                src = Wr; src2 = Wr + 2 * 16384;
                if (blockIdx.x == 0 && threadIdx.x < 128) {
                    const float* bl = conv_bl + (size_t)l * 4 * 128;
                    bsum[l * 128 + threadIdx.x] =
                        bl[threadIdx.x] + bl[2 * 128 + threadIdx.x];
                }
                break;
        }
    }
    int e = blockIdx.x * 256 + threadIdx.x;
    if (e < (K << 7)) {
        int n = (K == 128) ? (e >> 7) : (e >> 6);
        int k = e & (K - 1);
        float v = src[(size_t)k * 128 + n];
        if (src2) v += src2[(size_t)k * 128 + n];
        WT[(size_t)job * 16384 + n * K + k] = f2b(v);
    }
}

// ---------------------------------------------------------------------------
// CSR build (edges fixed within call; reused across layers)
__global__ __launch_bounds__(256) void hist_kernel(
    const int* __restrict__ e_card, const int* __restrict__ e_merch,
    int* __restrict__ hist_c, int* __restrict__ hist_m, int E)
{
    int i = blockIdx.x * 256 + threadIdx.x;
    if (i < E) {
        atomicAdd(&hist_c[e_card[i]], 1);
        atomicAdd(&hist_m[e_merch[i]], 1);
    }
}

__global__ __launch_bounds__(1024) void scan2_kernel(
    const int* __restrict__ hist_c, int* __restrict__ offs_c, int* __restrict__ cur_c, int nc,
    const int* __restrict__ hist_m, int* __restrict__ offs_m, int* __restrict__ cur_m, int nm)
{
    const int* hist = (blockIdx.x == 0) ? hist_c : hist_m;
    int* offs = (blockIdx.x == 0) ? offs_c : offs_m;
    int* cursor = (blockIdx.x == 0) ? cur_c : cur_m;
    int n = (blockIdx.x == 0) ? nc : nm;
    __shared__ int wsum[16];
    __shared__ int s_carry;
    const int tid = threadIdx.x, lane = tid & 63, wid = tid >> 6;
    if (tid == 0) s_carry = 0;
    __syncthreads();
    for (int base = 0; base < n; base += 1024) {
        int i = base + tid;
        int v = (i < n) ? hist[i] : 0;
        int x = v;
#pragma unroll
        for (int d = 1; d < 64; d <<= 1) {
            int t = __shfl_up(x, d);
            if (lane >= d) x += t;
        }
        if (lane == 63) wsum[wid] = x;
        __syncthreads();
        if (wid == 0) {
            int y = (lane < 16) ? wsum[lane] : 0;
#pragma unroll
            for (int d = 1; d < 16; d <<= 1) {
                int t = __shfl_up(y, d);
                if (lane >= d) y += t;
            }
            if (lane < 16) wsum[lane] = y;
        }
        __syncthreads();
        int wbase = (wid > 0) ? wsum[wid - 1] : 0;
        int excl = s_carry + wbase + x - v;
        if (i < n) { offs[i] = excl; cursor[i] = excl; }
        __syncthreads();
        if (tid == 0) s_carry += wsum[15];
        __syncthreads();
    }
    if (threadIdx.x == 0) offs[n] = s_carry;
}

__global__ __launch_bounds__(256) void place_kernel(
    const int* __restrict__ e_card, const int* __restrict__ e_tx_c,
    const int* __restrict__ e_merch, const int* __restrict__ e_tx_m,
    int* __restrict__ cur_c, int* __restrict__ eidx_c,
    int* __restrict__ cur_m, int* __restrict__ eidx_m, int E)
{
    int i = blockIdx.x * 256 + threadIdx.x;
    if (i < E) {
        int pc = atomicAdd(&cur_c[e_card[i]], 1);
        eidx_c[pc] = e_tx_c[i];
        int pm = atomicAdd(&cur_m[e_merch[i]], 1);
        eidx_m[pm] = e_tx_m[i];
    }
}

// one wave per dst node: mean of gathered bf16 h rows (4B/lane, coalesced)
__global__ __launch_bounds__(256) void gather_mean(
    const unsigned short* __restrict__ h_src, const int* __restrict__ offs,
    const int* __restrict__ eidx, unsigned short* __restrict__ out_mean, int n_dst)
{
    const int lane = threadIdx.x & 63;
    const int d = blockIdx.x * 4 + (threadIdx.x >> 6);
    if (d >= n_dst) return;
    const int s = offs[d], e = offs[d + 1];
    float a0 = 0.f, a1 = 0.f;
    for (int p = s; p < e; ++p) {
        int tx = eidx[p];
        unsigned v = *reinterpret_cast<const unsigned*>(
            h_src + (size_t)tx * 128 + lane * 2);
        a0 += b2f((unsigned short)(v & 0xffff));
        a1 += b2f((unsigned short)(v >> 16));
    }
    const float inv = (e > s) ? 1.0f / (float)(e - s) : 0.f;
    unsigned o = ((unsigned)f2b(a1 * inv) << 16) | f2b(a0 * inv);
    *reinterpret_cast<unsigned*>(out_mean + (size_t)d * 128 + lane * 2) = o;
}

// ---------------------------------------------------------------------------
extern "C" void kernel_launch(void* const* d_in, const int* in_sizes, int n_in,
                              void* d_out, int out_size, void* d_ws, size_t ws_size,
                              hipStream_t stream)
{
    const float* tx_x        = (const float*)d_in[0];
    const int*   card_ids    = (const int*)d_in[1];
    const int*   merch_ids   = (const int*)d_in[2];
    const int*   e_card      = (const int*)d_in[3];
    const int*   e_tx_c      = (const int*)d_in[4];
    const int*   e_merch     = (const int*)d_in[5];
    const int*   e_tx_m      = (const int*)d_in[6];
    const float* card_emb    = (const float*)d_in[7];
    const float* merch_emb   = (const float*)d_in[8];
    const float* card_proj_W = (const float*)d_in[9];
    const float* card_proj_b = (const float*)d_in[10];
    const float* merch_proj_W= (const float*)d_in[11];
    const float* merch_proj_b= (const float*)d_in[12];
    const float* tx_W        = (const float*)d_in[13];
    const float* tx_b        = (const float*)d_in[14];
    const float* conv_Wl     = (const float*)d_in[15];
    const float* conv_bl     = (const float*)d_in[16];
    const float* conv_Wr     = (const float*)d_in[17];
    const float* h1_W        = (const float*)d_in[18];
    const float* h1_b        = (const float*)d_in[19];
    const float* h2_W        = (const float*)d_in[20];
    const float* h2_b        = (const float*)d_in[21];

    char* wsb = (char*)d_ws;
    auto alloc = [&](size_t bytes) {
        char* p = wsb; wsb += (bytes + 255) & ~(size_t)255; return p;
    };
    unsigned short* tx_xb      = (unsigned short*)alloc((size_t)N_TX * 128 * 2);
    unsigned short* card_embb  = (unsigned short*)alloc((size_t)N_CARD * 64 * 2);
    unsigned short* merch_embb = (unsigned short*)alloc((size_t)N_MERCH * 64 * 2);
    unsigned short* h_tx       = (unsigned short*)alloc((size_t)N_TX * 128 * 2);
    unsigned short* h_card     = (unsigned short*)alloc((size_t)N_CARD * 128 * 2);
    unsigned short* h_merch    = (unsigned short*)alloc((size_t)N_MERCH * 128 * 2);
    unsigned short* p_card     = (unsigned short*)alloc((size_t)N_CARD * 128 * 2);
    unsigned short* p_merch    = (unsigned short*)alloc((size_t)N_MERCH * 128 * 2);
    unsigned short* mean_card  = (unsigned short*)alloc((size_t)N_CARD * 128 * 2);
    unsigned short* mean_merch = (unsigned short*)alloc((size_t)N_MERCH * 128 * 2);
    unsigned short* WT         = (unsigned short*)alloc((size_t)18 * 16384 * 2);
    float* bsum = (float*)alloc(2 * 128 * 4);
    int* hist_c = (int*)alloc((size_t)(N_CARD + N_MERCH) * 4);  // one memset
    int* hist_m = hist_c + N_CARD;
    int* offs_c = (int*)alloc((size_t)(N_CARD + 1) * 4);
    int* cur_c  = (int*)alloc((size_t)N_CARD * 4);
    int* eidx_c = (int*)alloc((size_t)NE * 4);
    int* offs_m = (int*)alloc((size_t)(N_MERCH + 1) * 4);
    int* cur_m  = (int*)alloc((size_t)N_MERCH * 4);
    int* eidx_m = (int*)alloc((size_t)NE * 4);

    auto WTj = [&](int job) { return WT + (size_t)job * 16384; };

    auto gemm128 = [&](const unsigned short* A1, const int* ri,
                       const unsigned short* W1, const unsigned short* A2,
                       const unsigned short* W2, const float* bias,
                       const unsigned short* P1, const int* I1,
                       const unsigned short* P2, const int* I2, int relu,
                       const float* h2w, const float* h2bb, void* out, int M) {
        mfma_gemm<128><<<dim3((M + 127) / 128), dim3(256), 0, stream>>>(
            A1, ri, W1, A2, W2, bias, P1, I1, P2, I2, relu, h2w, h2bb, out, M);
    };
    auto gemm64 = [&](const unsigned short* A1, const int* ri,
                      const unsigned short* W1, const float* bias,
                      int relu, void* out, int M) {
        mfma_gemm<64><<<dim3((M + 127) / 128), dim3(256), 0, stream>>>(
            A1, ri, W1, nullptr, nullptr, bias, nullptr, nullptr,
            nullptr, nullptr, relu, nullptr, nullptr, out, M);
    };
    auto cvt = [&](const float* s, unsigned short* d, int n) {
        f32_to_bf16<<<dim3((n / 8 + 255) / 256), dim3(256), 0, stream>>>(s, d, n);
    };

    // weight prep + activation converts + CSR build
    convert_weights<<<dim3(64, 18), dim3(256), 0, stream>>>(
        tx_W, card_proj_W, merch_proj_W, h1_W, conv_Wl, conv_Wr, conv_bl,
        WT, bsum);
    cvt(tx_x, tx_xb, N_TX * 128);
    cvt(card_emb, card_embb, N_CARD * 64);
    cvt(merch_emb, merch_embb, N_MERCH * 64);
    hipMemsetAsync(hist_c, 0, (size_t)(N_CARD + N_MERCH) * 4, stream);
    hist_kernel<<<dim3((NE + 255) / 256), dim3(256), 0, stream>>>(
        e_card, e_merch, hist_c, hist_m, NE);
    scan2_kernel<<<dim3(2), dim3(1024), 0, stream>>>(
        hist_c, offs_c, cur_c, N_CARD, hist_m, offs_m, cur_m, N_MERCH);
    place_kernel<<<dim3((NE + 255) / 256), dim3(256), 0, stream>>>(
        e_card, e_tx_c, e_merch, e_tx_m, cur_c, eidx_c, cur_m, eidx_m, NE);

    // input encoders
    gemm128(tx_xb, nullptr, WTj(0), nullptr, nullptr, tx_b,
            nullptr, nullptr, nullptr, nullptr, 1, nullptr, nullptr, h_tx, N_TX);
    gemm64(card_embb, card_ids, WTj(1), card_proj_b, 0, h_card, N_CARD);
    gemm64(merch_embb, merch_ids, WTj(2), merch_proj_b, 0, h_merch, N_MERCH);

    for (int l = 0; l < 2; ++l) {
        const float* bl = conv_bl + (size_t)l * 4 * 128;
        int j = 4 + l * 7;   // Wl0,Wl1,Wl2,Wl3,Wr1,Wr3,Wsum

        gather_mean<<<dim3((N_CARD + 3) / 4), dim3(256), 0, stream>>>(
            h_tx, offs_c, eidx_c, mean_card, N_CARD);
        gather_mean<<<dim3((N_MERCH + 3) / 4), dim3(256), 0, stream>>>(
            h_tx, offs_m, eidx_m, mean_merch, N_MERCH);

        // p_* = h_* @ Wl[0/2] (pre-update hidden) for the tx-side gather
        gemm128(h_card, nullptr, WTj(j + 0), nullptr, nullptr, nullptr,
                nullptr, nullptr, nullptr, nullptr, 0, nullptr, nullptr,
                p_card, N_CARD);
        gemm128(h_merch, nullptr, WTj(j + 2), nullptr, nullptr, nullptr,
                nullptr, nullptr, nullptr, nullptr, 0, nullptr, nullptr,
                p_merch, N_MERCH);

        // card/merch updates: relu(mean@Wl + h@Wr + bl)  (in-place, row-local)
        gemm128(mean_card, nullptr, WTj(j + 1), h_card, WTj(j + 4),
                bl + 1 * 128, nullptr, nullptr, nullptr, nullptr, 1,
                nullptr, nullptr, h_card, N_CARD);
        gemm128(mean_merch, nullptr, WTj(j + 3), h_merch, WTj(j + 5),
                bl + 3 * 128, nullptr, nullptr, nullptr, nullptr, 1,
                nullptr, nullptr, h_merch, N_MERCH);

        // tx update: relu(h_tx@(Wr0+Wr2) + bl0+bl2 + p_card[e_card] + p_merch[e_merch])
        gemm128(h_tx, nullptr, WTj(j + 6), nullptr, nullptr, bsum + l * 128,
                p_card, e_card, p_merch, e_merch, 1, nullptr, nullptr,
                h_tx, N_TX);
    }

    // head: logits = relu(h_tx @ h1_W + h1_b) @ h2_W + h2_b  (fp32 out)
    gemm128(h_tx, nullptr, WTj(3), nullptr, nullptr, h1_b,
            nullptr, nullptr, nullptr, nullptr, 1, h2_W, h2_b, d_out, N_TX);
}